// Round 1
// baseline (462.877 us; speedup 1.0000x reference)
//
#include <hip/hip_runtime.h>
#include <hip/hip_bf16.h>

#define NTOK 1024
#define HDIM 1024
#define IDIM 1024
#define NEXP 8
#define TWOI (2 * IDIM)

// workspace layout (bytes)
#define WS_COUNTS   0
#define WS_OFFSETS  32
#define WS_LTOK     64
#define WS_LK       (64 + 32768)
#define WS_LW       (64 + 65536)
#define WS_ACT      131072                      // 2048 x 1024 f32 = 8 MB
#define WS_TMP      (131072 + 2048 * 1024 * 4)  // 2 x 1024 x 1024 f32 = 8 MB

// ---------------- router: logits -> softmax scores -> top-2 -> expert lists ----
__global__ __launch_bounds__(64) void router_kernel(
    const float* __restrict__ flat, const float* __restrict__ rw,
    float* __restrict__ scores, int* __restrict__ counts,
    int* __restrict__ ltok, int* __restrict__ lk, float* __restrict__ lw)
{
    const int n = blockIdx.x;
    const int lane = threadIdx.x;
    float acc[NEXP];
#pragma unroll
    for (int e = 0; e < NEXP; ++e) acc[e] = 0.f;
    const float* xrow = flat + (size_t)n * HDIM;
    for (int h = lane; h < HDIM; h += 64) {
        float x = xrow[h];
#pragma unroll
        for (int e = 0; e < NEXP; ++e) acc[e] += x * rw[e * HDIM + h];
    }
#pragma unroll
    for (int e = 0; e < NEXP; ++e) {
#pragma unroll
        for (int off = 32; off > 0; off >>= 1)
            acc[e] += __shfl_down(acc[e], off);
    }
    if (lane == 0) {
        float m = acc[0];
#pragma unroll
        for (int e = 1; e < NEXP; ++e) m = fmaxf(m, acc[e]);
        float s = 0.f, p[NEXP];
#pragma unroll
        for (int e = 0; e < NEXP; ++e) { p[e] = __expf(acc[e] - m); s += p[e]; }
        float inv = 1.f / s;
#pragma unroll
        for (int e = 0; e < NEXP; ++e) { p[e] *= inv; scores[n * NEXP + e] = p[e]; }
        // top-2, ties -> lower index (strict >)
        int i0 = 0;
#pragma unroll
        for (int e = 1; e < NEXP; ++e) if (p[e] > p[i0]) i0 = e;
        int i1 = (i0 == 0) ? 1 : 0;
#pragma unroll
        for (int e = 0; e < NEXP; ++e) if (e != i0 && p[e] > p[i1]) i1 = e;
        int pos0 = atomicAdd(&counts[i0], 1);
        ltok[i0 * NTOK + pos0] = n; lk[i0 * NTOK + pos0] = 0; lw[i0 * NTOK + pos0] = p[i0];
        int pos1 = atomicAdd(&counts[i1], 1);
        ltok[i1 * NTOK + pos1] = n; lk[i1 * NTOK + pos1] = 1; lw[i1 * NTOK + pos1] = p[i1];
    }
}

__global__ void scan_kernel(const int* __restrict__ counts, int* __restrict__ offsets) {
    if (threadIdx.x == 0) {
        int acc = 0;
        for (int e = 0; e < NEXP; ++e) { offsets[e] = acc; acc += counts[e]; }
    }
}

// ---------------- GEMM1: gathered tokens x gate_up_proj[e], fused activation ----
// BM=64 tokens, BN=64 i-values (128 interleaved cols), BK=32
__global__ __launch_bounds__(256) void gemm1_kernel(
    const float* __restrict__ flat, const float* __restrict__ gup,
    const float* __restrict__ gbias,
    const int* __restrict__ counts, const int* __restrict__ offsets,
    const int* __restrict__ ltok, float* __restrict__ act)
{
    const int e = blockIdx.z;
    const int cnt = counts[e];
    const int by = blockIdx.y;
    if (by * 64 >= cnt) return;
    const int bx = blockIdx.x;
    const int off = offsets[e];
    const int t = threadIdx.x;
    const int tx = t & 15, ty = t >> 4;

    __shared__ float As[32][68];   // [k][token] transposed, stride 68 (16B-aligned, 2-way max)
    __shared__ float Bs[32][132];  // [k][col 0..127], stride 132
    __shared__ int   toks[64];

    if (t < 64) {
        int slot = by * 64 + t;
        toks[t] = ltok[e * NTOK + min(slot, cnt - 1)];
    }
    __syncthreads();

    float accg[4][4], accu[4][4];
#pragma unroll
    for (int a = 0; a < 4; ++a)
#pragma unroll
        for (int b = 0; b < 4; ++b) { accg[a][b] = 0.f; accu[a][b] = 0.f; }

    const size_t gup_base = (size_t)e * HDIM * TWOI + (size_t)bx * 128;

    for (int k0 = 0; k0 < HDIM; k0 += 32) {
        // stage A transposed: 64 tokens x 32 k, 2 float4 per thread
#pragma unroll
        for (int j = 0; j < 2; ++j) {
            int idx4 = t + 256 * j;          // 0..511
            int s = idx4 >> 3;               // token-in-tile 0..63
            int h4 = (idx4 & 7) * 4;         // 0..28
            const float4 v = *(const float4*)&flat[(size_t)toks[s] * HDIM + k0 + h4];
            As[h4 + 0][s] = v.x; As[h4 + 1][s] = v.y;
            As[h4 + 2][s] = v.z; As[h4 + 3][s] = v.w;
        }
        // stage B: 32 x 128, 4 float4 per thread, coalesced
#pragma unroll
        for (int j = 0; j < 4; ++j) {
            int idx4 = t + 256 * j;          // 0..1023
            int hh = idx4 >> 5;              // 0..31
            int c4 = (idx4 & 31) * 4;        // 0..124
            *(float4*)&Bs[hh][c4] =
                *(const float4*)&gup[gup_base + (size_t)(k0 + hh) * TWOI + c4];
        }
        __syncthreads();
#pragma unroll
        for (int kk = 0; kk < 32; ++kk) {
            const float4 a  = *(const float4*)&As[kk][4 * ty];
            const float4 b0 = *(const float4*)&Bs[kk][8 * tx];      // g0 u0 g1 u1
            const float4 b1 = *(const float4*)&Bs[kk][8 * tx + 4];  // g2 u2 g3 u3
            const float am[4] = {a.x, a.y, a.z, a.w};
#pragma unroll
            for (int mm = 0; mm < 4; ++mm) {
                accg[mm][0] += am[mm] * b0.x;  accu[mm][0] += am[mm] * b0.y;
                accg[mm][1] += am[mm] * b0.z;  accu[mm][1] += am[mm] * b0.w;
                accg[mm][2] += am[mm] * b1.x;  accu[mm][2] += am[mm] * b1.y;
                accg[mm][3] += am[mm] * b1.z;  accu[mm][3] += am[mm] * b1.w;
            }
        }
        __syncthreads();
    }

    const int ibase = bx * 64 + 4 * tx;
#pragma unroll
    for (int mm = 0; mm < 4; ++mm) {
        int slot = by * 64 + 4 * ty + mm;
        if (slot >= cnt) continue;
        float4 av;
        float* avp = (float*)&av;
#pragma unroll
        for (int ii = 0; ii < 4; ++ii) {
            int gi = ibase + ii;
            float g = accg[mm][ii] + gbias[e * TWOI + 2 * gi];
            float u = accu[mm][ii] + gbias[e * TWOI + 2 * gi + 1];
            g = fminf(g, 7.f);
            u = fminf(fmaxf(u, -7.f), 7.f);
            float sig = 1.f / (1.f + __expf(-1.702f * g));
            avp[ii] = (u + 1.f) * g * sig;
        }
        *(float4*)&act[(size_t)(off + slot) * IDIM + ibase] = av;
    }
}

// ---------------- GEMM2: activated x down_proj[e] -> weighted tmp[slot][token] ----
__global__ __launch_bounds__(256) void gemm2_kernel(
    const float* __restrict__ act, const float* __restrict__ dp,
    const float* __restrict__ dbias,
    const int* __restrict__ counts, const int* __restrict__ offsets,
    const int* __restrict__ ltok, const int* __restrict__ lk,
    const float* __restrict__ lw, float* __restrict__ tmp)
{
    const int e = blockIdx.z;
    const int cnt = counts[e];
    const int by = blockIdx.y;
    if (by * 64 >= cnt) return;
    const int bx = blockIdx.x;
    const int off = offsets[e];
    const int t = threadIdx.x;
    const int tx = t & 15, ty = t >> 4;

    __shared__ float As[32][68];
    __shared__ float Bs[32][68];
    __shared__ int   toks[64];
    __shared__ int   ksl[64];
    __shared__ float wts[64];

    if (t < 64) {
        int slot = by * 64 + t;
        int cl = min(slot, cnt - 1);
        toks[t] = ltok[e * NTOK + cl];
        ksl[t]  = lk[e * NTOK + cl];
        wts[t]  = lw[e * NTOK + cl];
    }
    __syncthreads();

    float acc[4][4];
#pragma unroll
    for (int a = 0; a < 4; ++a)
#pragma unroll
        for (int b = 0; b < 4; ++b) acc[a][b] = 0.f;

    for (int k0 = 0; k0 < IDIM; k0 += 32) {
#pragma unroll
        for (int j = 0; j < 2; ++j) {
            int idx4 = t + 256 * j;
            int s = idx4 >> 3;
            int h4 = (idx4 & 7) * 4;
            int row = off + min(by * 64 + s, cnt - 1);
            const float4 v = *(const float4*)&act[(size_t)row * IDIM + k0 + h4];
            As[h4 + 0][s] = v.x; As[h4 + 1][s] = v.y;
            As[h4 + 2][s] = v.z; As[h4 + 3][s] = v.w;
        }
#pragma unroll
        for (int j = 0; j < 2; ++j) {
            int idx4 = t + 256 * j;          // 0..511
            int hh = idx4 >> 4;              // 0..31
            int c4 = (idx4 & 15) * 4;        // 0..60
            *(float4*)&Bs[hh][c4] =
                *(const float4*)&dp[((size_t)e * IDIM + k0 + hh) * HDIM + bx * 64 + c4];
        }
        __syncthreads();
#pragma unroll
        for (int kk = 0; kk < 32; ++kk) {
            const float4 a = *(const float4*)&As[kk][4 * ty];
            const float4 b = *(const float4*)&Bs[kk][4 * tx];
            const float am[4] = {a.x, a.y, a.z, a.w};
            const float bm[4] = {b.x, b.y, b.z, b.w};
#pragma unroll
            for (int mm = 0; mm < 4; ++mm)
#pragma unroll
                for (int ii = 0; ii < 4; ++ii)
                    acc[mm][ii] += am[mm] * bm[ii];
        }
        __syncthreads();
    }

    const int hbase = bx * 64 + 4 * tx;
#pragma unroll
    for (int mm = 0; mm < 4; ++mm) {
        int sl = 4 * ty + mm;
        int slot = by * 64 + sl;
        if (slot >= cnt) continue;
        float w = wts[sl];
        int n = toks[sl], k = ksl[sl];
        float4 v;
        float* vp = (float*)&v;
#pragma unroll
        for (int ii = 0; ii < 4; ++ii)
            vp[ii] = (acc[mm][ii] + dbias[e * HDIM + hbase + ii]) * w;
        *(float4*)&tmp[((size_t)k * NTOK + n) * HDIM + hbase] = v;
    }
}

// ---------------- combine: out = tmp[0] + tmp[1] ----------------
__global__ __launch_bounds__(256) void combine_kernel(
    const float* __restrict__ tmp, float* __restrict__ out)
{
    int i = blockIdx.x * blockDim.x + threadIdx.x;  // float4 index, exact cover
    const float4 a = ((const float4*)tmp)[i];
    const float4 b = ((const float4*)(tmp + (size_t)NTOK * HDIM))[i];
    float4 o;
    o.x = a.x + b.x; o.y = a.y + b.y; o.z = a.z + b.z; o.w = a.w + b.w;
    ((float4*)out)[i] = o;
}

extern "C" void kernel_launch(void* const* d_in, const int* in_sizes, int n_in,
                              void* d_out, int out_size, void* d_ws, size_t ws_size,
                              hipStream_t stream) {
    const float* flat  = (const float*)d_in[0];
    const float* rw    = (const float*)d_in[1];
    const float* gup   = (const float*)d_in[2];
    const float* gbias = (const float*)d_in[3];
    const float* dp    = (const float*)d_in[4];
    const float* dbias = (const float*)d_in[5];
    float* out    = (float*)d_out;
    float* scores = out + (size_t)NTOK * HDIM;

    char* ws = (char*)d_ws;
    int*   counts  = (int*)(ws + WS_COUNTS);
    int*   offsets = (int*)(ws + WS_OFFSETS);
    int*   ltok    = (int*)(ws + WS_LTOK);
    int*   lkb     = (int*)(ws + WS_LK);
    float* lw      = (float*)(ws + WS_LW);
    float* act     = (float*)(ws + WS_ACT);
    float* tmp     = (float*)(ws + WS_TMP);

    hipMemsetAsync(counts, 0, 32, stream);
    router_kernel<<<NTOK, 64, 0, stream>>>(flat, rw, scores, counts, ltok, lkb, lw);
    scan_kernel<<<1, 1, 0, stream>>>(counts, offsets);
    gemm1_kernel<<<dim3(16, 16, NEXP), 256, 0, stream>>>(flat, gup, gbias, counts, offsets, ltok, act);
    gemm2_kernel<<<dim3(16, 16, NEXP), 256, 0, stream>>>(act, dp, dbias, counts, offsets, ltok, lkb, lw, tmp);
    combine_kernel<<<1024, 256, 0, stream>>>(tmp, out);
}

// Round 2
// 129.050 us; speedup vs baseline: 3.5868x; 3.5868x over previous
//
#include <hip/hip_runtime.h>
#include <hip/hip_bf16.h>

typedef __attribute__((ext_vector_type(8))) short short8;
typedef __attribute__((ext_vector_type(4))) float f32x4;

#define NTOK 1024
#define HDIM 1024
#define IDIM 1024
#define NEXP 8
#define NCOL 2048  // 2*I interleaved gate/up

// ---- workspace layout (bytes) ----
#define WS_COUNTS   0
#define WS_OFFSETS  256
#define WS_LTOK     1024
#define WS_LK       (WS_LTOK + NEXP*NTOK*4)
#define WS_LW       (WS_LK + NEXP*NTOK*4)
#define WS_XBF      131072                                   // 1024x1024 bf16 = 2 MB
#define WS_ACT      (WS_XBF + NTOK*HDIM*2)                   // 2048x1024 bf16 = 4 MB
#define WS_TMP      (WS_ACT + 2*NTOK*IDIM*2)                 // 2x1024x1024 f32 = 8 MB
#define WS_W1T      (WS_TMP + 2*NTOK*HDIM*4)                 // 8x2048x1024 bf16 = 32 MB
#define WS_W2T      (WS_W1T + (size_t)NEXP*NCOL*HDIM*2)      // 8x1024x1024 bf16 = 16 MB

static __device__ __forceinline__ unsigned short f2bf(float x) {
    __hip_bfloat16 h = __float2bfloat16(x);   // RNE
    return __builtin_bit_cast(unsigned short, h);
}

#define GLDS16(g, l) __builtin_amdgcn_global_load_lds( \
    (const __attribute__((address_space(1))) void*)(g), \
    (__attribute__((address_space(3))) void*)(l), 16, 0, 0)

// ---------------- router: logits -> softmax -> top-2 lists; also writes Xbf ----
__global__ __launch_bounds__(64) void router_kernel(
    const float* __restrict__ flat, const float* __restrict__ rw,
    float* __restrict__ scores, int* __restrict__ counts,
    int* __restrict__ ltok, int* __restrict__ lk, float* __restrict__ lw,
    unsigned short* __restrict__ xbf)
{
    const int n = blockIdx.x;
    const int l = threadIdx.x;
    float acc[NEXP];
#pragma unroll
    for (int e = 0; e < NEXP; ++e) acc[e] = 0.f;
    const float* xrow = flat + (size_t)n * HDIM;
#pragma unroll
    for (int j = 0; j < 4; ++j) {
        int h = j * 256 + l * 4;
        float4 v = *(const float4*)&xrow[h];
        ushort4 xb;
        xb.x = f2bf(v.x); xb.y = f2bf(v.y); xb.z = f2bf(v.z); xb.w = f2bf(v.w);
        *(ushort4*)&xbf[(size_t)n * HDIM + h] = xb;
#pragma unroll
        for (int e = 0; e < NEXP; ++e) {
            float4 wv = *(const float4*)&rw[e * HDIM + h];
            acc[e] += v.x * wv.x + v.y * wv.y + v.z * wv.z + v.w * wv.w;
        }
    }
#pragma unroll
    for (int e = 0; e < NEXP; ++e) {
#pragma unroll
        for (int off = 32; off > 0; off >>= 1)
            acc[e] += __shfl_down(acc[e], off);
    }
    if (l == 0) {
        float m = acc[0];
#pragma unroll
        for (int e = 1; e < NEXP; ++e) m = fmaxf(m, acc[e]);
        float s = 0.f, p[NEXP];
#pragma unroll
        for (int e = 0; e < NEXP; ++e) { p[e] = __expf(acc[e] - m); s += p[e]; }
        float inv = 1.f / s;
#pragma unroll
        for (int e = 0; e < NEXP; ++e) { p[e] *= inv; scores[n * NEXP + e] = p[e]; }
        int i0 = 0;
#pragma unroll
        for (int e = 1; e < NEXP; ++e) if (p[e] > p[i0]) i0 = e;
        int i1 = (i0 == 0) ? 1 : 0;
#pragma unroll
        for (int e = 0; e < NEXP; ++e) if (e != i0 && p[e] > p[i1]) i1 = e;
        int pos0 = atomicAdd(&counts[i0], 1);
        ltok[i0 * NTOK + pos0] = n; lk[i0 * NTOK + pos0] = 0; lw[i0 * NTOK + pos0] = p[i0];
        int pos1 = atomicAdd(&counts[i1], 1);
        ltok[i1 * NTOK + pos1] = n; lk[i1 * NTOK + pos1] = 1; lw[i1 * NTOK + pos1] = p[i1];
    }
}

__global__ void scan_kernel(const int* __restrict__ counts, int* __restrict__ offsets) {
    if (threadIdx.x == 0) {
        int acc = 0;
        for (int e = 0; e < NEXP; ++e) { offsets[e] = acc; acc += counts[e]; }
    }
}

// ---------------- fused convert fp32 -> bf16 + transpose per expert ----
// src[e][nrows][ncols] (f32) -> dst[e][ncols][nrows] (bf16). grid(ncols/64, nrows/64, E)
__global__ __launch_bounds__(256) void transpose_bf16_kernel(
    const float* __restrict__ src, unsigned short* __restrict__ dst,
    int nrows, int ncols)
{
    const int e = blockIdx.z, rb = blockIdx.y, cb = blockIdx.x;
    __shared__ unsigned short tile[64][66];
    const int t = threadIdx.x;
    {
        const int r = t >> 2, c4 = (t & 3) * 16;
        const float* s = src + ((size_t)e * nrows + (size_t)(rb * 64 + r)) * ncols + cb * 64 + c4;
#pragma unroll
        for (int q = 0; q < 4; ++q) {
            float4 v = *(const float4*)(s + q * 4);
            ushort4 o;
            o.x = f2bf(v.x); o.y = f2bf(v.y); o.z = f2bf(v.z); o.w = f2bf(v.w);
            *(ushort4*)&tile[r][c4 + q * 4] = o;
        }
    }
    __syncthreads();
    {
        const int c = t >> 2, r4 = (t & 3) * 16;
        unsigned short* d = dst + ((size_t)e * ncols + (size_t)(cb * 64 + c)) * nrows + rb * 64 + r4;
#pragma unroll
        for (int q = 0; q < 4; ++q) {
            ushort4 o;
            o.x = tile[r4 + q * 4 + 0][c];
            o.y = tile[r4 + q * 4 + 1][c];
            o.z = tile[r4 + q * 4 + 2][c];
            o.w = tile[r4 + q * 4 + 3][c];
            *(ushort4*)&d[q * 4] = o;
        }
    }
}

// ---------------- GEMM1: act[slot][i] = f(Xbf[tok] @ W1t[e]) fused activation ----
// tile 64 slots x 64 cols (of 2048 interleaved), BK=64, 2 waves, wave-tile 64x32
__global__ __launch_bounds__(128) void gemm1_kernel(
    const unsigned short* __restrict__ xbf, const unsigned short* __restrict__ w1t,
    const float* __restrict__ gbias,
    const int* __restrict__ counts, const int* __restrict__ offsets,
    const int* __restrict__ ltok, unsigned short* __restrict__ act)
{
    const int e = blockIdx.z;
    const int cnt = counts[e];
    const int by = blockIdx.y;
    if (by * 64 >= cnt) return;
    const int bx = blockIdx.x;
    const int off = offsets[e];
    const int t = threadIdx.x;
    const int l = t & 63, w = t >> 6;

    __shared__ unsigned short As[2][64][64];
    __shared__ unsigned short Bs[2][64][64];
    __shared__ int toks[64];
    if (t < 64) toks[t] = ltok[e * NTOK + min(by * 64 + t, cnt - 1)];
    __syncthreads();

    // glds source addresses. Lane i of wave-load a lands at LDS row a*8+(i>>3),
    // chunk (i&7). Source fetches k-chunk (i&7)^(i>>3) -> both-sides XOR swizzle.
    const int li = l & 7, lr = l >> 3;
    const int kswz = (li ^ lr) * 8;                  // shorts
    const unsigned short* asrc[4];
    const unsigned short* bsrc[4];
#pragma unroll
    for (int j = 0; j < 4; ++j) {
        int a = w * 4 + j;
        int rr = a * 8 + lr;
        asrc[j] = xbf + (size_t)toks[rr] * HDIM + kswz;
        bsrc[j] = w1t + ((size_t)e * NCOL + bx * 64 + rr) * HDIM + kswz;
    }

    f32x4 acc[4][2];
#pragma unroll
    for (int m = 0; m < 4; ++m)
#pragma unroll
        for (int n = 0; n < 2; ++n) acc[m][n] = 0.f;

#pragma unroll
    for (int j = 0; j < 4; ++j) {
        GLDS16(asrc[j], &As[0][(w * 4 + j) * 8][0]);
        GLDS16(bsrc[j], &Bs[0][(w * 4 + j) * 8][0]);
    }
    __syncthreads();

    const int lg = l >> 4, lo = l & 15;
    // swizzled read chunk offsets for k-halves q=0,1 (global chunk q*4+lg at
    // LDS chunk (q*4+lg)^(row&7), row&7 == lo&7 for all fragment rows)
    const int cA0 = ((0 + lg) ^ (lo & 7)) * 8;
    const int cA1 = ((4 + lg) ^ (lo & 7)) * 8;

    for (int ks = 0; ks < HDIM / 64; ++ks) {
        const int p = ks & 1;
        if (ks + 1 < HDIM / 64) {
            const int kadv = (ks + 1) * 64;
#pragma unroll
            for (int j = 0; j < 4; ++j) {
                GLDS16(asrc[j] + kadv, &As[p ^ 1][(w * 4 + j) * 8][0]);
                GLDS16(bsrc[j] + kadv, &Bs[p ^ 1][(w * 4 + j) * 8][0]);
            }
        }
#pragma unroll
        for (int q = 0; q < 2; ++q) {
            const int cq = q ? cA1 : cA0;
            short8 a0 = *(const short8*)&As[p][ 0 + lo][cq];
            short8 a1 = *(const short8*)&As[p][16 + lo][cq];
            short8 a2 = *(const short8*)&As[p][32 + lo][cq];
            short8 a3 = *(const short8*)&As[p][48 + lo][cq];
            short8 b0 = *(const short8*)&Bs[p][w * 32 +  0 + lo][cq];
            short8 b1 = *(const short8*)&Bs[p][w * 32 + 16 + lo][cq];
            acc[0][0] = __builtin_amdgcn_mfma_f32_16x16x32_bf16(a0, b0, acc[0][0], 0, 0, 0);
            acc[1][0] = __builtin_amdgcn_mfma_f32_16x16x32_bf16(a1, b0, acc[1][0], 0, 0, 0);
            acc[2][0] = __builtin_amdgcn_mfma_f32_16x16x32_bf16(a2, b0, acc[2][0], 0, 0, 0);
            acc[3][0] = __builtin_amdgcn_mfma_f32_16x16x32_bf16(a3, b0, acc[3][0], 0, 0, 0);
            acc[0][1] = __builtin_amdgcn_mfma_f32_16x16x32_bf16(a0, b1, acc[0][1], 0, 0, 0);
            acc[1][1] = __builtin_amdgcn_mfma_f32_16x16x32_bf16(a1, b1, acc[1][1], 0, 0, 0);
            acc[2][1] = __builtin_amdgcn_mfma_f32_16x16x32_bf16(a2, b1, acc[2][1], 0, 0, 0);
            acc[3][1] = __builtin_amdgcn_mfma_f32_16x16x32_bf16(a3, b1, acc[3][1], 0, 0, 0);
        }
        __syncthreads();
    }

    // epilogue: pair (gate,up) live in adjacent lanes (col parity == lane parity)
    const int rj = (l >> 4) * 4;
#pragma unroll
    for (int m = 0; m < 4; ++m) {
#pragma unroll
        for (int n = 0; n < 2; ++n) {
            int col = bx * 64 + w * 32 + n * 16 + lo;
            float bias = gbias[e * NCOL + col];
#pragma unroll
            for (int j = 0; j < 4; ++j) {
                int slot = by * 64 + m * 16 + rj + j;
                float val = acc[m][n][j] + bias;
                float other = __shfl_xor(val, 1);
                float g = (l & 1) ? other : val;
                float u = (l & 1) ? val : other;
                g = fminf(g, 7.f);
                u = fminf(fmaxf(u, -7.f), 7.f);
                float av = (u + 1.f) * g * (1.f / (1.f + __expf(-1.702f * g)));
                if (!(l & 1) && slot < cnt)
                    act[(size_t)(off + slot) * IDIM + (col >> 1)] = f2bf(av);
            }
        }
    }
}

// ---------------- GEMM2: tmp[k][tok][h] = (act @ W2t[e] + bias) * w ----
__global__ __launch_bounds__(128) void gemm2_kernel(
    const unsigned short* __restrict__ act, const unsigned short* __restrict__ w2t,
    const float* __restrict__ dbias,
    const int* __restrict__ counts, const int* __restrict__ offsets,
    const int* __restrict__ ltok, const int* __restrict__ lkb,
    const float* __restrict__ lw, float* __restrict__ tmp)
{
    const int e = blockIdx.z;
    const int cnt = counts[e];
    const int by = blockIdx.y;
    if (by * 64 >= cnt) return;
    const int bx = blockIdx.x;
    const int off = offsets[e];
    const int t = threadIdx.x;
    const int l = t & 63, w = t >> 6;

    __shared__ unsigned short As[2][64][64];
    __shared__ unsigned short Bs[2][64][64];
    __shared__ int toks[64];
    __shared__ int ksl[64];
    __shared__ float wts[64];
    if (t < 64) {
        int cl = min(by * 64 + t, cnt - 1);
        toks[t] = ltok[e * NTOK + cl];
        ksl[t]  = lkb[e * NTOK + cl];
        wts[t]  = lw[e * NTOK + cl];
    }
    __syncthreads();

    const int li = l & 7, lr = l >> 3;
    const int kswz = (li ^ lr) * 8;
    const unsigned short* asrc[4];
    const unsigned short* bsrc[4];
#pragma unroll
    for (int j = 0; j < 4; ++j) {
        int a = w * 4 + j;
        int rr = a * 8 + lr;
        asrc[j] = act + (size_t)(off + min(by * 64 + rr, cnt - 1)) * IDIM + kswz;
        bsrc[j] = w2t + ((size_t)e * HDIM + bx * 64 + rr) * IDIM + kswz;
    }

    f32x4 acc[4][2];
#pragma unroll
    for (int m = 0; m < 4; ++m)
#pragma unroll
        for (int n = 0; n < 2; ++n) acc[m][n] = 0.f;

#pragma unroll
    for (int j = 0; j < 4; ++j) {
        GLDS16(asrc[j], &As[0][(w * 4 + j) * 8][0]);
        GLDS16(bsrc[j], &Bs[0][(w * 4 + j) * 8][0]);
    }
    __syncthreads();

    const int lg = l >> 4, lo = l & 15;
    const int cA0 = ((0 + lg) ^ (lo & 7)) * 8;
    const int cA1 = ((4 + lg) ^ (lo & 7)) * 8;

    for (int ks = 0; ks < IDIM / 64; ++ks) {
        const int p = ks & 1;
        if (ks + 1 < IDIM / 64) {
            const int kadv = (ks + 1) * 64;
#pragma unroll
            for (int j = 0; j < 4; ++j) {
                GLDS16(asrc[j] + kadv, &As[p ^ 1][(w * 4 + j) * 8][0]);
                GLDS16(bsrc[j] + kadv, &Bs[p ^ 1][(w * 4 + j) * 8][0]);
            }
        }
#pragma unroll
        for (int q = 0; q < 2; ++q) {
            const int cq = q ? cA1 : cA0;
            short8 a0 = *(const short8*)&As[p][ 0 + lo][cq];
            short8 a1 = *(const short8*)&As[p][16 + lo][cq];
            short8 a2 = *(const short8*)&As[p][32 + lo][cq];
            short8 a3 = *(const short8*)&As[p][48 + lo][cq];
            short8 b0 = *(const short8*)&Bs[p][w * 32 +  0 + lo][cq];
            short8 b1 = *(const short8*)&Bs[p][w * 32 + 16 + lo][cq];
            acc[0][0] = __builtin_amdgcn_mfma_f32_16x16x32_bf16(a0, b0, acc[0][0], 0, 0, 0);
            acc[1][0] = __builtin_amdgcn_mfma_f32_16x16x32_bf16(a1, b0, acc[1][0], 0, 0, 0);
            acc[2][0] = __builtin_amdgcn_mfma_f32_16x16x32_bf16(a2, b0, acc[2][0], 0, 0, 0);
            acc[3][0] = __builtin_amdgcn_mfma_f32_16x16x32_bf16(a3, b0, acc[3][0], 0, 0, 0);
            acc[0][1] = __builtin_amdgcn_mfma_f32_16x16x32_bf16(a0, b1, acc[0][1], 0, 0, 0);
            acc[1][1] = __builtin_amdgcn_mfma_f32_16x16x32_bf16(a1, b1, acc[1][1], 0, 0, 0);
            acc[2][1] = __builtin_amdgcn_mfma_f32_16x16x32_bf16(a2, b1, acc[2][1], 0, 0, 0);
            acc[3][1] = __builtin_amdgcn_mfma_f32_16x16x32_bf16(a3, b1, acc[3][1], 0, 0, 0);
        }
        __syncthreads();
    }

    const int rj = (l >> 4) * 4;
#pragma unroll
    for (int m = 0; m < 4; ++m) {
#pragma unroll
        for (int n = 0; n < 2; ++n) {
            int col = bx * 64 + w * 32 + n * 16 + lo;
            float bias = dbias[e * HDIM + col];
#pragma unroll
            for (int j = 0; j < 4; ++j) {
                int sl = m * 16 + rj + j;
                int slot = by * 64 + sl;
                if (slot < cnt) {
                    float val = (acc[m][n][j] + bias) * wts[sl];
                    tmp[((size_t)ksl[sl] * NTOK + toks[sl]) * HDIM + col] = val;
                }
            }
        }
    }
}

// ---------------- combine: out = tmp[0] + tmp[1] ----------------
__global__ __launch_bounds__(256) void combine_kernel(
    const float* __restrict__ tmp, float* __restrict__ out)
{
    int i = blockIdx.x * blockDim.x + threadIdx.x;
    const float4 a = ((const float4*)tmp)[i];
    const float4 b = ((const float4*)(tmp + (size_t)NTOK * HDIM))[i];
    float4 o;
    o.x = a.x + b.x; o.y = a.y + b.y; o.z = a.z + b.z; o.w = a.w + b.w;
    ((float4*)out)[i] = o;
}

extern "C" void kernel_launch(void* const* d_in, const int* in_sizes, int n_in,
                              void* d_out, int out_size, void* d_ws, size_t ws_size,
                              hipStream_t stream) {
    const float* flat  = (const float*)d_in[0];
    const float* rw    = (const float*)d_in[1];
    const float* gup   = (const float*)d_in[2];
    const float* gbias = (const float*)d_in[3];
    const float* dp    = (const float*)d_in[4];
    const float* dbias = (const float*)d_in[5];
    float* out    = (float*)d_out;
    float* scores = out + (size_t)NTOK * HDIM;

    char* ws = (char*)d_ws;
    int*   counts  = (int*)(ws + WS_COUNTS);
    int*   offsets = (int*)(ws + WS_OFFSETS);
    int*   ltok    = (int*)(ws + WS_LTOK);
    int*   lkb     = (int*)(ws + WS_LK);
    float* lw      = (float*)(ws + WS_LW);
    unsigned short* xbf = (unsigned short*)(ws + WS_XBF);
    unsigned short* act = (unsigned short*)(ws + WS_ACT);
    float* tmp     = (float*)(ws + WS_TMP);
    unsigned short* w1t = (unsigned short*)(ws + WS_W1T);
    unsigned short* w2t = (unsigned short*)(ws + WS_W2T);

    hipMemsetAsync(counts, 0, 32, stream);
    router_kernel<<<NTOK, 64, 0, stream>>>(flat, rw, scores, counts, ltok, lkb, lw, xbf);
    scan_kernel<<<1, 1, 0, stream>>>(counts, offsets);
    transpose_bf16_kernel<<<dim3(NCOL / 64, HDIM / 64, NEXP), 256, 0, stream>>>(gup, w1t, HDIM, NCOL);
    transpose_bf16_kernel<<<dim3(HDIM / 64, IDIM / 64, NEXP), 256, 0, stream>>>(dp, w2t, IDIM, HDIM);
    gemm1_kernel<<<dim3(NCOL / 64, NTOK / 64, NEXP), 128, 0, stream>>>(xbf, w1t, gbias, counts, offsets, ltok, act);
    gemm2_kernel<<<dim3(HDIM / 64, NTOK / 64, NEXP), 128, 0, stream>>>(act, w2t, dbias, counts, offsets, ltok, lkb, lw, tmp);
    combine_kernel<<<1024, 256, 0, stream>>>(tmp, out);
}

// Round 3
// 125.563 us; speedup vs baseline: 3.6864x; 1.0278x over previous
//
#include <hip/hip_runtime.h>
#include <hip/hip_bf16.h>

typedef __attribute__((ext_vector_type(8))) short short8;
typedef __attribute__((ext_vector_type(4))) float f32x4;

#define NTOK 1024
#define HDIM 1024
#define IDIM 1024
#define NEXP 8
#define NCOL 2048  // 2*I interleaved gate/up

// ---- workspace layout (bytes) ----
#define WS_COUNTS   0
#define WS_OFFSETS  256
#define WS_LTOK     1024
#define WS_LK       (WS_LTOK + NEXP*NTOK*4)
#define WS_LW       (WS_LK + NEXP*NTOK*4)
#define WS_XBF      131072                                   // 1024x1024 bf16 = 2 MB
#define WS_ACT      (WS_XBF + NTOK*HDIM*2)                   // 2048x1024 bf16 = 4 MB
#define WS_TMP      (WS_ACT + 2*NTOK*IDIM*2)                 // 2x1024x1024 f32 = 8 MB
#define WS_W1T      (WS_TMP + 2*NTOK*HDIM*4)                 // 8x2048x1024 bf16 = 32 MB
#define WS_W2T      (WS_W1T + (size_t)NEXP*NCOL*HDIM*2)      // 8x1024x1024 bf16 = 16 MB

static __device__ __forceinline__ unsigned short f2bf(float x) {
    __hip_bfloat16 h = __float2bfloat16(x);   // RNE
    return __builtin_bit_cast(unsigned short, h);
}

#define GLDS16(g, l) __builtin_amdgcn_global_load_lds( \
    (const __attribute__((address_space(1))) void*)(g), \
    (__attribute__((address_space(3))) void*)(l), 16, 0, 0)

// ---------------- router: logits -> softmax -> top-2 lists; also writes Xbf ----
__global__ __launch_bounds__(64) void router_kernel(
    const float* __restrict__ flat, const float* __restrict__ rw,
    float* __restrict__ scores, int* __restrict__ counts,
    int* __restrict__ ltok, int* __restrict__ lk, float* __restrict__ lw,
    unsigned short* __restrict__ xbf)
{
    const int n = blockIdx.x;
    const int l = threadIdx.x;
    float acc[NEXP];
#pragma unroll
    for (int e = 0; e < NEXP; ++e) acc[e] = 0.f;
    const float* xrow = flat + (size_t)n * HDIM;
#pragma unroll
    for (int j = 0; j < 4; ++j) {
        int h = j * 256 + l * 4;
        float4 v = *(const float4*)&xrow[h];
        ushort4 xb;
        xb.x = f2bf(v.x); xb.y = f2bf(v.y); xb.z = f2bf(v.z); xb.w = f2bf(v.w);
        *(ushort4*)&xbf[(size_t)n * HDIM + h] = xb;
#pragma unroll
        for (int e = 0; e < NEXP; ++e) {
            float4 wv = *(const float4*)&rw[e * HDIM + h];
            acc[e] += v.x * wv.x + v.y * wv.y + v.z * wv.z + v.w * wv.w;
        }
    }
#pragma unroll
    for (int e = 0; e < NEXP; ++e) {
#pragma unroll
        for (int off = 32; off > 0; off >>= 1)
            acc[e] += __shfl_down(acc[e], off);
    }
    if (l == 0) {
        float m = acc[0];
#pragma unroll
        for (int e = 1; e < NEXP; ++e) m = fmaxf(m, acc[e]);
        float s = 0.f, p[NEXP];
#pragma unroll
        for (int e = 0; e < NEXP; ++e) { p[e] = __expf(acc[e] - m); s += p[e]; }
        float inv = 1.f / s;
#pragma unroll
        for (int e = 0; e < NEXP; ++e) { p[e] *= inv; scores[n * NEXP + e] = p[e]; }
        int i0 = 0;
#pragma unroll
        for (int e = 1; e < NEXP; ++e) if (p[e] > p[i0]) i0 = e;
        int i1 = (i0 == 0) ? 1 : 0;
#pragma unroll
        for (int e = 0; e < NEXP; ++e) if (e != i0 && p[e] > p[i1]) i1 = e;
        int pos0 = atomicAdd(&counts[i0], 1);
        ltok[i0 * NTOK + pos0] = n; lk[i0 * NTOK + pos0] = 0; lw[i0 * NTOK + pos0] = p[i0];
        int pos1 = atomicAdd(&counts[i1], 1);
        ltok[i1 * NTOK + pos1] = n; lk[i1 * NTOK + pos1] = 1; lw[i1 * NTOK + pos1] = p[i1];
    }
}

__global__ void scan_kernel(const int* __restrict__ counts, int* __restrict__ offsets) {
    if (threadIdx.x == 0) {
        int acc = 0;
        for (int e = 0; e < NEXP; ++e) { offsets[e] = acc; acc += counts[e]; }
    }
}

// ---------------- fused convert fp32 -> bf16 + transpose per expert ----
// src[e][nrows][ncols] (f32) -> dst[e][ncols][nrows] (bf16). grid(ncols/64, nrows/64, E)
// Read: float4/lane fully coalesced. Write: 16B/lane (short8), 128B per 8-lane group.
// LDS tile [64][65] fp32: both phases <=2-way banks.
__global__ __launch_bounds__(256) void transpose_bf16_kernel(
    const float* __restrict__ src, unsigned short* __restrict__ dst,
    int nrows, int ncols)
{
    const int e = blockIdx.z, rb = blockIdx.y, cb = blockIdx.x;
    __shared__ float tile[64][65];
    const int t = threadIdx.x;
    {
        const int r0 = t >> 4, c4 = (t & 15) * 4;
#pragma unroll
        for (int p = 0; p < 4; ++p) {
            int r = p * 16 + r0;
            float4 v = *(const float4*)&src[((size_t)e * nrows + rb * 64 + r) * ncols + cb * 64 + c4];
            tile[r][c4 + 0] = v.x; tile[r][c4 + 1] = v.y;
            tile[r][c4 + 2] = v.z; tile[r][c4 + 3] = v.w;
        }
    }
    __syncthreads();
    {
        const int c0 = t >> 3, r8 = (t & 7) * 8;
#pragma unroll
        for (int p = 0; p < 2; ++p) {
            int c = p * 32 + c0;
            short8 o;
#pragma unroll
            for (int i = 0; i < 8; ++i) o[i] = (short)f2bf(tile[r8 + i][c]);
            *(short8*)&dst[((size_t)e * ncols + cb * 64 + c) * nrows + rb * 64 + r8] = o;
        }
    }
}

// ---------------- GEMM1: act[slot][i] = f(Xbf[tok] @ W1t[e]) fused activation ----
// BM=128 slots x BN=128 cols, BK=64, 256 thr / 4 waves (2x2), wave-tile 64x64
__global__ __launch_bounds__(256) void gemm1_kernel(
    const unsigned short* __restrict__ xbf, const unsigned short* __restrict__ w1t,
    const float* __restrict__ gbias,
    const int* __restrict__ counts, const int* __restrict__ offsets,
    const int* __restrict__ ltok, unsigned short* __restrict__ act)
{
    const int e = blockIdx.z;
    const int cnt = counts[e];
    const int by = blockIdx.y;
    if (by * 128 >= cnt) return;
    const int bx = blockIdx.x;
    const int off = offsets[e];
    const int t = threadIdx.x;
    const int l = t & 63, w = t >> 6;
    const int wm = w >> 1, wn = w & 1;

    __shared__ unsigned short As[2][128][64];
    __shared__ unsigned short Bs[2][128][64];
    __shared__ int toks[128];
    if (t < 128) toks[t] = ltok[e * NTOK + min(by * 128 + t, cnt - 1)];
    __syncthreads();

    // glds: lane i of wave-load a lands at LDS row a*8+(i>>3), chunk (i&7).
    // Source fetches k-chunk (i&7)^(i>>3) -> both-sides XOR swizzle (R2-proven).
    const int li = l & 7, lr = l >> 3;
    const int kswz = (li ^ lr) * 8;                  // shorts
    const unsigned short* asrc[4];
    const unsigned short* bsrc[4];
#pragma unroll
    for (int j = 0; j < 4; ++j) {
        int rr = (w * 4 + j) * 8 + lr;
        asrc[j] = xbf + (size_t)toks[rr] * HDIM + kswz;
        bsrc[j] = w1t + ((size_t)e * NCOL + bx * 128 + rr) * HDIM + kswz;
    }

    f32x4 acc[4][4];
#pragma unroll
    for (int m = 0; m < 4; ++m)
#pragma unroll
        for (int n = 0; n < 4; ++n) acc[m][n] = 0.f;

#pragma unroll
    for (int j = 0; j < 4; ++j) {
        GLDS16(asrc[j], &As[0][(w * 4 + j) * 8][0]);
        GLDS16(bsrc[j], &Bs[0][(w * 4 + j) * 8][0]);
    }
    __syncthreads();

    const int lg = l >> 4, lo = l & 15;
    const int cq0 = ((0 + lg) ^ (lo & 7)) * 8;   // LDS chunk offset (shorts), k-half 0
    const int cq1 = ((4 + lg) ^ (lo & 7)) * 8;   // k-half 1

    for (int ks = 0; ks < HDIM / 64; ++ks) {
        const int p = ks & 1;
        if (ks + 1 < HDIM / 64) {
            const int kadv = (ks + 1) * 64;
#pragma unroll
            for (int j = 0; j < 4; ++j) {
                GLDS16(asrc[j] + kadv, &As[p ^ 1][(w * 4 + j) * 8][0]);
                GLDS16(bsrc[j] + kadv, &Bs[p ^ 1][(w * 4 + j) * 8][0]);
            }
        }
#pragma unroll
        for (int q = 0; q < 2; ++q) {
            const int cq = q ? cq1 : cq0;
            short8 a0 = *(const short8*)&As[p][wm * 64 +  0 + lo][cq];
            short8 a1 = *(const short8*)&As[p][wm * 64 + 16 + lo][cq];
            short8 a2 = *(const short8*)&As[p][wm * 64 + 32 + lo][cq];
            short8 a3 = *(const short8*)&As[p][wm * 64 + 48 + lo][cq];
            short8 b0 = *(const short8*)&Bs[p][wn * 64 +  0 + lo][cq];
            short8 b1 = *(const short8*)&Bs[p][wn * 64 + 16 + lo][cq];
            short8 b2 = *(const short8*)&Bs[p][wn * 64 + 32 + lo][cq];
            short8 b3 = *(const short8*)&Bs[p][wn * 64 + 48 + lo][cq];
#pragma unroll
            for (int m = 0; m < 4; ++m) {
                short8 am = (m == 0) ? a0 : (m == 1) ? a1 : (m == 2) ? a2 : a3;
                acc[m][0] = __builtin_amdgcn_mfma_f32_16x16x32_bf16(am, b0, acc[m][0], 0, 0, 0);
                acc[m][1] = __builtin_amdgcn_mfma_f32_16x16x32_bf16(am, b1, acc[m][1], 0, 0, 0);
                acc[m][2] = __builtin_amdgcn_mfma_f32_16x16x32_bf16(am, b2, acc[m][2], 0, 0, 0);
                acc[m][3] = __builtin_amdgcn_mfma_f32_16x16x32_bf16(am, b3, acc[m][3], 0, 0, 0);
            }
        }
        __syncthreads();
    }

    // epilogue: (gate,up) pairs live in adjacent lanes (col parity == lane parity)
    const int rj = lg * 4;
#pragma unroll
    for (int m = 0; m < 4; ++m) {
#pragma unroll
        for (int n = 0; n < 4; ++n) {
            int col = bx * 128 + wn * 64 + n * 16 + lo;
            float bias = gbias[e * NCOL + col];
#pragma unroll
            for (int j = 0; j < 4; ++j) {
                int slot = by * 128 + wm * 64 + m * 16 + rj + j;
                float val = acc[m][n][j] + bias;
                float other = __shfl_xor(val, 1);
                float g = (l & 1) ? other : val;
                float u = (l & 1) ? val : other;
                g = fminf(g, 7.f);
                u = fminf(fmaxf(u, -7.f), 7.f);
                float av = (u + 1.f) * g * (1.f / (1.f + __expf(-1.702f * g)));
                if (!(l & 1) && slot < cnt)
                    act[(size_t)(off + slot) * IDIM + (col >> 1)] = f2bf(av);
            }
        }
    }
}

// ---------------- GEMM2: tmp[k][tok][h] = (act @ W2t[e] + bias) * w ----
__global__ __launch_bounds__(256) void gemm2_kernel(
    const unsigned short* __restrict__ act, const unsigned short* __restrict__ w2t,
    const float* __restrict__ dbias,
    const int* __restrict__ counts, const int* __restrict__ offsets,
    const int* __restrict__ ltok, const int* __restrict__ lkb,
    const float* __restrict__ lw, float* __restrict__ tmp)
{
    const int e = blockIdx.z;
    const int cnt = counts[e];
    const int by = blockIdx.y;
    if (by * 128 >= cnt) return;
    const int bx = blockIdx.x;
    const int off = offsets[e];
    const int t = threadIdx.x;
    const int l = t & 63, w = t >> 6;
    const int wm = w >> 1, wn = w & 1;

    __shared__ unsigned short As[2][128][64];
    __shared__ unsigned short Bs[2][128][64];
    __shared__ int toks[128];
    __shared__ int ksl[128];
    __shared__ float wts[128];
    if (t < 128) {
        int cl = min(by * 128 + t, cnt - 1);
        toks[t] = ltok[e * NTOK + cl];
        ksl[t]  = lkb[e * NTOK + cl];
        wts[t]  = lw[e * NTOK + cl];
    }
    __syncthreads();

    const int li = l & 7, lr = l >> 3;
    const int kswz = (li ^ lr) * 8;
    const unsigned short* asrc[4];
    const unsigned short* bsrc[4];
#pragma unroll
    for (int j = 0; j < 4; ++j) {
        int rr = (w * 4 + j) * 8 + lr;
        asrc[j] = act + (size_t)(off + min(by * 128 + rr, cnt - 1)) * IDIM + kswz;
        bsrc[j] = w2t + ((size_t)e * HDIM + bx * 128 + rr) * IDIM + kswz;
    }

    f32x4 acc[4][4];
#pragma unroll
    for (int m = 0; m < 4; ++m)
#pragma unroll
        for (int n = 0; n < 4; ++n) acc[m][n] = 0.f;

#pragma unroll
    for (int j = 0; j < 4; ++j) {
        GLDS16(asrc[j], &As[0][(w * 4 + j) * 8][0]);
        GLDS16(bsrc[j], &Bs[0][(w * 4 + j) * 8][0]);
    }
    __syncthreads();

    const int lg = l >> 4, lo = l & 15;
    const int cq0 = ((0 + lg) ^ (lo & 7)) * 8;
    const int cq1 = ((4 + lg) ^ (lo & 7)) * 8;

    for (int ks = 0; ks < IDIM / 64; ++ks) {
        const int p = ks & 1;
        if (ks + 1 < IDIM / 64) {
            const int kadv = (ks + 1) * 64;
#pragma unroll
            for (int j = 0; j < 4; ++j) {
                GLDS16(asrc[j] + kadv, &As[p ^ 1][(w * 4 + j) * 8][0]);
                GLDS16(bsrc[j] + kadv, &Bs[p ^ 1][(w * 4 + j) * 8][0]);
            }
        }
#pragma unroll
        for (int q = 0; q < 2; ++q) {
            const int cq = q ? cq1 : cq0;
            short8 a0 = *(const short8*)&As[p][wm * 64 +  0 + lo][cq];
            short8 a1 = *(const short8*)&As[p][wm * 64 + 16 + lo][cq];
            short8 a2 = *(const short8*)&As[p][wm * 64 + 32 + lo][cq];
            short8 a3 = *(const short8*)&As[p][wm * 64 + 48 + lo][cq];
            short8 b0 = *(const short8*)&Bs[p][wn * 64 +  0 + lo][cq];
            short8 b1 = *(const short8*)&Bs[p][wn * 64 + 16 + lo][cq];
            short8 b2 = *(const short8*)&Bs[p][wn * 64 + 32 + lo][cq];
            short8 b3 = *(const short8*)&Bs[p][wn * 64 + 48 + lo][cq];
#pragma unroll
            for (int m = 0; m < 4; ++m) {
                short8 am = (m == 0) ? a0 : (m == 1) ? a1 : (m == 2) ? a2 : a3;
                acc[m][0] = __builtin_amdgcn_mfma_f32_16x16x32_bf16(am, b0, acc[m][0], 0, 0, 0);
                acc[m][1] = __builtin_amdgcn_mfma_f32_16x16x32_bf16(am, b1, acc[m][1], 0, 0, 0);
                acc[m][2] = __builtin_amdgcn_mfma_f32_16x16x32_bf16(am, b2, acc[m][2], 0, 0, 0);
                acc[m][3] = __builtin_amdgcn_mfma_f32_16x16x32_bf16(am, b3, acc[m][3], 0, 0, 0);
            }
        }
        __syncthreads();
    }

    const int rj = lg * 4;
#pragma unroll
    for (int m = 0; m < 4; ++m) {
#pragma unroll
        for (int n = 0; n < 4; ++n) {
            int col = bx * 128 + wn * 64 + n * 16 + lo;
            float bias = dbias[e * HDIM + col];
#pragma unroll
            for (int j = 0; j < 4; ++j) {
                int sl = wm * 64 + m * 16 + rj + j;
                int slot = by * 128 + sl;
                if (slot < cnt) {
                    float val = (acc[m][n][j] + bias) * wts[sl];
                    tmp[((size_t)ksl[sl] * NTOK + toks[sl]) * HDIM + col] = val;
                }
            }
        }
    }
}

// ---------------- combine: out = tmp[0] + tmp[1] ----------------
__global__ __launch_bounds__(256) void combine_kernel(
    const float* __restrict__ tmp, float* __restrict__ out)
{
    int i = blockIdx.x * blockDim.x + threadIdx.x;
    const float4 a = ((const float4*)tmp)[i];
    const float4 b = ((const float4*)(tmp + (size_t)NTOK * HDIM))[i];
    float4 o;
    o.x = a.x + b.x; o.y = a.y + b.y; o.z = a.z + b.z; o.w = a.w + b.w;
    ((float4*)out)[i] = o;
}

extern "C" void kernel_launch(void* const* d_in, const int* in_sizes, int n_in,
                              void* d_out, int out_size, void* d_ws, size_t ws_size,
                              hipStream_t stream) {
    const float* flat  = (const float*)d_in[0];
    const float* rw    = (const float*)d_in[1];
    const float* gup   = (const float*)d_in[2];
    const float* gbias = (const float*)d_in[3];
    const float* dp    = (const float*)d_in[4];
    const float* dbias = (const float*)d_in[5];
    float* out    = (float*)d_out;
    float* scores = out + (size_t)NTOK * HDIM;

    char* ws = (char*)d_ws;
    int*   counts  = (int*)(ws + WS_COUNTS);
    int*   offsets = (int*)(ws + WS_OFFSETS);
    int*   ltok    = (int*)(ws + WS_LTOK);
    int*   lkb     = (int*)(ws + WS_LK);
    float* lw      = (float*)(ws + WS_LW);
    unsigned short* xbf = (unsigned short*)(ws + WS_XBF);
    unsigned short* act = (unsigned short*)(ws + WS_ACT);
    float* tmp     = (float*)(ws + WS_TMP);
    unsigned short* w1t = (unsigned short*)(ws + WS_W1T);
    unsigned short* w2t = (unsigned short*)(ws + WS_W2T);

    hipMemsetAsync(counts, 0, 32, stream);
    router_kernel<<<NTOK, 64, 0, stream>>>(flat, rw, scores, counts, ltok, lkb, lw, xbf);
    scan_kernel<<<1, 1, 0, stream>>>(counts, offsets);
    transpose_bf16_kernel<<<dim3(NCOL / 64, HDIM / 64, NEXP), 256, 0, stream>>>(gup, w1t, HDIM, NCOL);
    transpose_bf16_kernel<<<dim3(HDIM / 64, IDIM / 64, NEXP), 256, 0, stream>>>(dp, w2t, IDIM, HDIM);
    gemm1_kernel<<<dim3(16, 8, NEXP), 256, 0, stream>>>(xbf, w1t, gbias, counts, offsets, ltok, act);
    gemm2_kernel<<<dim3(8, 8, NEXP), 256, 0, stream>>>(act, w2t, dbias, counts, offsets, ltok, lkb, lw, tmp);
    combine_kernel<<<1024, 256, 0, stream>>>(tmp, out);
}